// Round 1
// baseline (39.892 us; speedup 1.0000x reference)
//
#include <hip/hip_runtime.h>

#define HDIM 1024
#define GS 8
#define NBR 4.0f

// ---------------------------------------------------------------------------
// Kernel 1: compute cell per agent, per-cell counts, and a compacted list of
// masked agents. Entry encoding: i*64 + cell.
// ---------------------------------------------------------------------------
__global__ void k_cells(const float2* __restrict__ pos, const int* __restrict__ idxp,
                        int n, int* __restrict__ counts, int* __restrict__ list,
                        int* __restrict__ m)
{
    __shared__ int hist[64];
    __shared__ int lbuf[256];
    __shared__ int lcnt;
    __shared__ int lbase;

    int tid = threadIdx.x;
    if (tid < 64) hist[tid] = 0;
    if (tid == 0) lcnt = 0;
    __syncthreads();

    int idx = idxp[0];
    float2 p0 = pos[idx];

    int i = blockIdx.x * blockDim.x + tid;
    if (i < n) {
        float2 p = pos[i];
        float dx = p.x - p0.x;
        float dy = p.y - p0.y;
        bool mask = (fmaxf(fabsf(dx), fabsf(dy)) <= NBR) && (i != idx);
        if (mask) {
            float vx = (dx / NBR + 1.0f) * 0.5f * (float)GS;
            float vy = (dy / NBR + 1.0f) * 0.5f * (float)GS;
            vx = fminf(fmaxf(vx, 0.0f), (float)(GS - 1));
            vy = fminf(fmaxf(vy, 0.0f), (float)(GS - 1));
            int gx = (int)vx;   // truncation == floor (vx >= 0)
            int gy = (int)vy;
            int c = gy * GS + gx;
            atomicAdd(&hist[c], 1);
            int p_in = atomicAdd(&lcnt, 1);
            lbuf[p_in] = i * 64 + c;
        }
    }
    __syncthreads();

    if (tid == 0) lbase = atomicAdd(m, lcnt);
    if (tid < 64 && hist[tid] > 0) atomicAdd(&counts[tid], hist[tid]);
    __syncthreads();

    if (tid < lcnt) list[lbase + tid] = lbuf[tid];
}

// ---------------------------------------------------------------------------
// Kernel 2: weighted row reduction over the compacted list.
// Each thread owns 4 columns (float4). Per-block partial row written to ws.
// ---------------------------------------------------------------------------
__global__ void k_reduce(const float* __restrict__ h, const int* __restrict__ list,
                         const int* __restrict__ m_ptr, const int* __restrict__ counts,
                         float* __restrict__ partials)
{
    __shared__ float inv[64];
    int tid = threadIdx.x;
    if (tid < 64) {
        int c = counts[tid];
        inv[tid] = 1.0f / (float)(c > 1 ? c : 1);
    }
    __syncthreads();

    int m = m_ptr[0];
    float4 acc = make_float4(0.f, 0.f, 0.f, 0.f);
    const int stride = gridDim.x * 4;

    for (int base = blockIdx.x * 4; base < m; base += stride) {
        int e0 = list[base];
        int e1 = (base + 1 < m) ? list[base + 1] : -1;
        int e2 = (base + 2 < m) ? list[base + 2] : -1;
        int e3 = (base + 3 < m) ? list[base + 3] : -1;

        // issue all row loads before consuming (ILP)
        float4 v0 = ((const float4*)(h + (size_t)(e0 >> 6) * HDIM))[tid];
        float4 v1, v2, v3;
        if (e1 >= 0) v1 = ((const float4*)(h + (size_t)(e1 >> 6) * HDIM))[tid];
        if (e2 >= 0) v2 = ((const float4*)(h + (size_t)(e2 >> 6) * HDIM))[tid];
        if (e3 >= 0) v3 = ((const float4*)(h + (size_t)(e3 >> 6) * HDIM))[tid];

        float w0 = inv[e0 & 63];
        acc.x += w0 * v0.x; acc.y += w0 * v0.y; acc.z += w0 * v0.z; acc.w += w0 * v0.w;
        if (e1 >= 0) {
            float w = inv[e1 & 63];
            acc.x += w * v1.x; acc.y += w * v1.y; acc.z += w * v1.z; acc.w += w * v1.w;
        }
        if (e2 >= 0) {
            float w = inv[e2 & 63];
            acc.x += w * v2.x; acc.y += w * v2.y; acc.z += w * v2.z; acc.w += w * v2.w;
        }
        if (e3 >= 0) {
            float w = inv[e3 & 63];
            acc.x += w * v3.x; acc.y += w * v3.y; acc.z += w * v3.z; acc.w += w * v3.w;
        }
    }

    ((float4*)(partials + (size_t)blockIdx.x * HDIM))[tid] = acc;
}

// ---------------------------------------------------------------------------
// Kernel 3: combine partial rows into pooled (few atomics per address).
// ---------------------------------------------------------------------------
__global__ void k_combine(const float* __restrict__ partials, float* __restrict__ pooled,
                          int nrows)
{
    int tid = threadIdx.x;
    int per = nrows / gridDim.x;
    int b0 = blockIdx.x * per;
    float s0 = 0.f, s1 = 0.f, s2 = 0.f, s3 = 0.f;
    for (int b = b0; b < b0 + per; ++b) {
        const float* row = partials + (size_t)b * HDIM;
        s0 += row[tid];
        s1 += row[tid + 256];
        s2 += row[tid + 512];
        s3 += row[tid + 768];
    }
    atomicAdd(&pooled[tid],        s0);
    atomicAdd(&pooled[tid + 256],  s1);
    atomicAdd(&pooled[tid + 512],  s2);
    atomicAdd(&pooled[tid + 768],  s3);
}

// ---------------------------------------------------------------------------
// Kernel 4: out[j] = W[j,:] . pooled + b[j]
// ---------------------------------------------------------------------------
__global__ void k_matvec(const float* __restrict__ W, const float* __restrict__ bvec,
                         const float* __restrict__ pooled, float* __restrict__ out)
{
    int j = blockIdx.x;
    int tid = threadIdx.x;

    float4 wv = ((const float4*)(W + (size_t)j * HDIM))[tid];
    float4 pv = ((const float4*)pooled)[tid];
    float d = wv.x * pv.x + wv.y * pv.y + wv.z * pv.z + wv.w * pv.w;

    // wave64 reduction
    for (int off = 32; off > 0; off >>= 1)
        d += __shfl_down(d, off, 64);

    __shared__ float red[4];
    int wave = tid >> 6;
    if ((tid & 63) == 0) red[wave] = d;
    __syncthreads();
    if (tid == 0)
        out[j] = red[0] + red[1] + red[2] + red[3] + bvec[j];
}

extern "C" void kernel_launch(void* const* d_in, const int* in_sizes, int n_in,
                              void* d_out, int out_size, void* d_ws, size_t ws_size,
                              hipStream_t stream) {
    const float*  h    = (const float*)d_in[0];
    const float2* pos  = (const float2*)d_in[1];
    const int*    idxp = (const int*)d_in[2];
    const float*  W    = (const float*)d_in[3];
    const float*  bvec = (const float*)d_in[4];
    float* out = (float*)d_out;

    int n = in_sizes[0] / HDIM;   // number of agents

    const int NB_REDUCE = 512;

    char* ws = (char*)d_ws;
    int*   list     = (int*)ws;                                   // n ints
    size_t off      = (((size_t)n * 4) + 511) & ~(size_t)511;
    int*   counts   = (int*)(ws + off);                           // 64 ints
    int*   m        = (int*)(ws + off + 256);                     // 1 int
    float* pooled   = (float*)(ws + off + 512);                   // 1024 floats
    float* partials = (float*)(ws + off + 512 + 4096);            // NB_REDUCE * 1024 floats

    // zero counts + m + pooled (ws is poisoned, and not re-poisoned between replays)
    hipMemsetAsync(ws + off, 0, 512 + 4096, stream);

    int blocks1 = (n + 255) / 256;
    k_cells<<<blocks1, 256, 0, stream>>>(pos, idxp, n, counts, list, m);
    k_reduce<<<NB_REDUCE, 256, 0, stream>>>(h, list, m, counts, partials);
    k_combine<<<32, 256, 0, stream>>>(partials, pooled, NB_REDUCE);
    k_matvec<<<HDIM, 256, 0, stream>>>(W, bvec, pooled, out);
}

// Round 2
// 39.734 us; speedup vs baseline: 1.0040x; 1.0040x over previous
//
#include <hip/hip_runtime.h>

#define HDIM 1024
#define GS 8
#define NBR 4.0f

// ---------------------------------------------------------------------------
// Kernel 1: compute cell per agent, per-cell counts, and a compacted list of
// masked agents. Entry encoding: i*64 + cell.
// ---------------------------------------------------------------------------
__global__ void k_cells(const float2* __restrict__ pos, const int* __restrict__ idxp,
                        int n, int* __restrict__ counts, int* __restrict__ list,
                        int* __restrict__ m)
{
    __shared__ int hist[64];
    __shared__ int lbuf[256];
    __shared__ int lcnt;
    __shared__ int lbase;

    int tid = threadIdx.x;
    if (tid < 64) hist[tid] = 0;
    if (tid == 0) lcnt = 0;
    __syncthreads();

    int idx = idxp[0];
    float2 p0 = pos[idx];

    int i = blockIdx.x * blockDim.x + tid;
    if (i < n) {
        float2 p = pos[i];
        float dx = p.x - p0.x;
        float dy = p.y - p0.y;
        bool mask = (fmaxf(fabsf(dx), fabsf(dy)) <= NBR) && (i != idx);
        if (mask) {
            float vx = (dx / NBR + 1.0f) * 0.5f * (float)GS;
            float vy = (dy / NBR + 1.0f) * 0.5f * (float)GS;
            vx = fminf(fmaxf(vx, 0.0f), (float)(GS - 1));
            vy = fminf(fmaxf(vy, 0.0f), (float)(GS - 1));
            int gx = (int)vx;   // truncation == floor (vx >= 0)
            int gy = (int)vy;
            int c = gy * GS + gx;
            atomicAdd(&hist[c], 1);
            int p_in = atomicAdd(&lcnt, 1);
            lbuf[p_in] = i * 64 + c;
        }
    }
    __syncthreads();

    if (tid == 0) lbase = atomicAdd(m, lcnt);
    if (tid < 64 && hist[tid] > 0) atomicAdd(&counts[tid], hist[tid]);
    __syncthreads();

    if (tid < lcnt) list[lbase + tid] = lbuf[tid];
}

// ---------------------------------------------------------------------------
// Kernel 2: weighted row reduction over the compacted list.
// Each thread owns 4 columns (float4). Per-block partial row written to ws.
// ---------------------------------------------------------------------------
__global__ void k_reduce(const float* __restrict__ h, const int* __restrict__ list,
                         const int* __restrict__ m_ptr, const int* __restrict__ counts,
                         float* __restrict__ partials)
{
    __shared__ float inv[64];
    int tid = threadIdx.x;
    if (tid < 64) {
        int c = counts[tid];
        inv[tid] = 1.0f / (float)(c > 1 ? c : 1);
    }
    __syncthreads();

    int m = m_ptr[0];
    float4 acc = make_float4(0.f, 0.f, 0.f, 0.f);
    const int stride = gridDim.x * 4;

    for (int base = blockIdx.x * 4; base < m; base += stride) {
        int e0 = list[base];
        int e1 = (base + 1 < m) ? list[base + 1] : -1;
        int e2 = (base + 2 < m) ? list[base + 2] : -1;
        int e3 = (base + 3 < m) ? list[base + 3] : -1;

        // issue all row loads before consuming (ILP / memory-level parallelism)
        float4 v0 = ((const float4*)(h + (size_t)(e0 >> 6) * HDIM))[tid];
        float4 v1, v2, v3;
        if (e1 >= 0) v1 = ((const float4*)(h + (size_t)(e1 >> 6) * HDIM))[tid];
        if (e2 >= 0) v2 = ((const float4*)(h + (size_t)(e2 >> 6) * HDIM))[tid];
        if (e3 >= 0) v3 = ((const float4*)(h + (size_t)(e3 >> 6) * HDIM))[tid];

        float w0 = inv[e0 & 63];
        acc.x += w0 * v0.x; acc.y += w0 * v0.y; acc.z += w0 * v0.z; acc.w += w0 * v0.w;
        if (e1 >= 0) {
            float w = inv[e1 & 63];
            acc.x += w * v1.x; acc.y += w * v1.y; acc.z += w * v1.z; acc.w += w * v1.w;
        }
        if (e2 >= 0) {
            float w = inv[e2 & 63];
            acc.x += w * v2.x; acc.y += w * v2.y; acc.z += w * v2.z; acc.w += w * v2.w;
        }
        if (e3 >= 0) {
            float w = inv[e3 & 63];
            acc.x += w * v3.x; acc.y += w * v3.y; acc.z += w * v3.z; acc.w += w * v3.w;
        }
    }

    ((float4*)(partials + (size_t)blockIdx.x * HDIM))[tid] = acc;
}

// ---------------------------------------------------------------------------
// Kernel 3: combine partial rows into pooled (few atomics per address).
// ---------------------------------------------------------------------------
__global__ void k_combine(const float* __restrict__ partials, float* __restrict__ pooled,
                          int nrows)
{
    int tid = threadIdx.x;
    int per = nrows / gridDim.x;
    int b0 = blockIdx.x * per;
    float s0 = 0.f, s1 = 0.f, s2 = 0.f, s3 = 0.f;
    for (int b = b0; b < b0 + per; ++b) {
        const float* row = partials + (size_t)b * HDIM;
        s0 += row[tid];
        s1 += row[tid + 256];
        s2 += row[tid + 512];
        s3 += row[tid + 768];
    }
    atomicAdd(&pooled[tid],        s0);
    atomicAdd(&pooled[tid + 256],  s1);
    atomicAdd(&pooled[tid + 512],  s2);
    atomicAdd(&pooled[tid + 768],  s3);
}

// ---------------------------------------------------------------------------
// Kernel 4: out[j] = W[j,:] . pooled + b[j]   (one row per wave, 4 rows/block)
// ---------------------------------------------------------------------------
__global__ void k_matvec(const float* __restrict__ W, const float* __restrict__ bvec,
                         const float* __restrict__ pooled, float* __restrict__ out)
{
    int tid  = threadIdx.x;       // 0..255
    int wave = tid >> 6;          // 0..3
    int lane = tid & 63;
    int j = blockIdx.x * 4 + wave;

    const float4* Wr = (const float4*)(W + (size_t)j * HDIM);
    const float4* P  = (const float4*)pooled;

    float d = 0.f;
#pragma unroll
    for (int q = 0; q < 4; ++q) {
        float4 wv = Wr[lane + q * 64];
        float4 pv = P[lane + q * 64];
        d += wv.x * pv.x + wv.y * pv.y + wv.z * pv.z + wv.w * pv.w;
    }

    for (int off = 32; off > 0; off >>= 1)
        d += __shfl_down(d, off, 64);

    if (lane == 0)
        out[j] = d + bvec[j];
}

extern "C" void kernel_launch(void* const* d_in, const int* in_sizes, int n_in,
                              void* d_out, int out_size, void* d_ws, size_t ws_size,
                              hipStream_t stream) {
    const float*  h    = (const float*)d_in[0];
    const float2* pos  = (const float2*)d_in[1];
    const int*    idxp = (const int*)d_in[2];
    const float*  W    = (const float*)d_in[3];
    const float*  bvec = (const float*)d_in[4];
    float* out = (float*)d_out;

    int n = in_sizes[0] / HDIM;   // number of agents

    char* ws = (char*)d_ws;
    int*   list     = (int*)ws;                                   // n ints
    size_t off      = (((size_t)n * 4) + 511) & ~(size_t)511;
    int*   counts   = (int*)(ws + off);                           // 64 ints
    int*   m        = (int*)(ws + off + 256);                     // 1 int
    float* pooled   = (float*)(ws + off + 512);                   // 1024 floats
    float* partials = (float*)(ws + off + 512 + 4096);            // NB_REDUCE * 1024 floats

    // pick reduce-grid size that fits the workspace
    size_t fixed = off + 512 + 4096;
    int NB_REDUCE = 1024;
    while (NB_REDUCE > 128 && fixed + (size_t)NB_REDUCE * HDIM * 4 > ws_size)
        NB_REDUCE >>= 1;

    // zero counts + m + pooled (ws is poisoned, and not re-poisoned between replays)
    hipMemsetAsync(ws + off, 0, 512 + 4096, stream);

    int blocks1 = (n + 255) / 256;
    k_cells<<<blocks1, 256, 0, stream>>>(pos, idxp, n, counts, list, m);
    k_reduce<<<NB_REDUCE, 256, 0, stream>>>(h, list, m, counts, partials);
    k_combine<<<64, 256, 0, stream>>>(partials, pooled, NB_REDUCE);
    k_matvec<<<HDIM / 4, 256, 0, stream>>>(W, bvec, pooled, out);
}